// Round 8
// baseline (71.205 us; speedup 1.0000x reference)
//
#include <hip/hip_runtime.h>

namespace {
constexpr int NPER = 512;    // blocks per segment
constexpr int UU   = 4;      // units per block
constexpr int KK   = 16;     // k
constexpr int NB   = 4096;   // total blocks
constexpr int NK   = NB * KK;
constexpr int DST  = 9;      // doubles per candidate (72B): 6 data + 3 pad
constexpr int REPEAT = 4;    // DIAGNOSTIC: run the full body 4x (idempotent
                             // output rewrites) so the dispatch exceeds the
                             // 40us harness fills and surfaces in top-5
                             // rocprof rows, and so per-rep time amortizes
                             // any fixed launch/ramp overhead.

// ---- packed dual-f32 (VOP3P). Each half is an exact IEEE _rn f32 op. ----
union pk2 { double d; float f[2]; unsigned u[2]; };

__device__ __forceinline__ double mkpk(float lo, float hi) {
    pk2 t; t.f[0] = lo; t.f[1] = hi; return t.d;
}
__device__ __forceinline__ double pk_mul(double a, double b) {
    double r; asm("v_pk_mul_f32 %0, %1, %2" : "=v"(r) : "v"(a), "v"(b)); return r;
}
__device__ __forceinline__ double pk_add(double a, double b) {
    double r; asm("v_pk_add_f32 %0, %1, %2" : "=v"(r) : "v"(a), "v"(b)); return r;
}
__device__ __forceinline__ double pk_fma(double a, double b, double c) {
    double r; asm("v_pk_fma_f32 %0, %1, %2, %3" : "=v"(r) : "v"(a), "v"(b), "v"(c)); return r;
}

// ---- f32 wave min via DPP: 6 steps x {dpp mov, v_min_f32}; uniform result. ----
__device__ __forceinline__ float wave_min_f32(float v) {
    constexpr int PINF = 0x7F800000;
    int x = __float_as_int(v);
    #define DPP_MIN(CTRL, RM)                                                  \
        x = __float_as_int(fminf(__int_as_float(x), __int_as_float(            \
                __builtin_amdgcn_update_dpp(PINF, x, CTRL, RM, 0xF, false))));
    DPP_MIN(0x111, 0xF)  // row_shr:1
    DPP_MIN(0x112, 0xF)  // row_shr:2
    DPP_MIN(0x114, 0xF)  // row_shr:4
    DPP_MIN(0x118, 0xF)  // row_shr:8
    DPP_MIN(0x142, 0xA)  // row_bcast:15 -> rows 1,3
    DPP_MIN(0x143, 0xC)  // row_bcast:31 -> rows 2,3
    #undef DPP_MIN
    return __int_as_float(__builtin_amdgcn_readlane(x, 63));
}

__global__ __launch_bounds__(256) void knn_edge_kernel(const float* __restrict__ unit_pos,
                                                       int* __restrict__ out) {
    __shared__ double spd[NPER * DST];               // 36864 B
    float* sfl = reinterpret_cast<float*>(spd);

    const int wg  = blockIdx.x;        // 1024 WGs; 4 rows (waves) each
    const int seg = (wg * 4) >> 9;     // / NPER
    const int tid = threadIdx.x;
    const int wave = tid >> 6;
    const int lane = tid & 63;
    const int r_local  = (wg * 4 + wave) & (NPER - 1);
    const int r_global = seg * NPER + r_local;

    #pragma unroll 1
    for (int rep = 0; rep < REPEAT; ++rep) {
        // Stage segment positions, pair-SoA per candidate:
        // [x0 x1 x2 x3 | y0..y3 | z0..z3 | pad x6], stride 18 floats.
        {
            const float4* g4 = reinterpret_cast<const float4*>(
                unit_pos + (size_t)seg * NPER * UU * 3);
            #pragma unroll
            for (int jj = 0; jj < 6; ++jj) {
                const int i4 = tid + 256 * jj;     // float4 index 0..1535
                const float4 v = g4[i4];
                const int c = i4 / 3;
                const int rem = (i4 - 3 * c) * 4;  // 0, 4, or 8
                const float vv[4] = {v.x, v.y, v.z, v.w};
                #pragma unroll
                for (int e = 0; e < 4; ++e) {
                    const int j = rem + e, u = j / 3, ax = j - 3 * u;
                    sfl[c * (2 * DST) + ax * 4 + u] = vv[e];
                }
            }
        }
        __syncthreads();

        // Row units duplicated into pk pairs + norms (uniform broadcast reads).
        double xi_p[UU], yi_p[UU], zi_p[UU], ai_p[UU];
        {
            const float* rp = &sfl[r_local * (2 * DST)];
            #pragma unroll
            for (int u = 0; u < UU; ++u) {
                const float x = rp[0 * 4 + u], y = rp[1 * 4 + u], z = rp[2 * 4 + u];
                const float a = __fadd_rn(__fadd_rn(__fmul_rn(x, x), __fmul_rn(y, y)),
                                          __fmul_rn(z, z));
                xi_p[u] = mkpk(x, x); yi_p[u] = mkpk(y, y);
                zi_p[u] = mkpk(z, z); ai_p[u] = mkpk(a, a);
            }
        }
        const double m2 = mkpk(-2.0f, -2.0f);

        // Each lane owns candidates c = lane + 64*t. Packed math halves are the
        // reference's exact f32 ops (left-assoc adds; fma(dot,-2,sum) ==
        // fsub(sum, fmul(2,dot)) since 2*dot is exact).
        float dist[8];
        #pragma unroll
        for (int t = 0; t < 8; ++t) {
            const int c = lane + 64 * t;
            const double* cp = &spd[c * DST];
            const double x01 = cp[0], x23 = cp[1];
            const double y01 = cp[2], y23 = cp[3];
            const double z01 = cp[4], z23 = cp[5];
            const double aj01 = pk_add(pk_add(pk_mul(x01, x01), pk_mul(y01, y01)),
                                       pk_mul(z01, z01));
            const double aj23 = pk_add(pk_add(pk_mul(x23, x23), pk_mul(y23, y23)),
                                       pk_mul(z23, z23));
            pk2 h[8];
            #pragma unroll
            for (int u = 0; u < UU; ++u) {
                const double dot01 = pk_add(pk_add(pk_mul(xi_p[u], x01),
                                                   pk_mul(yi_p[u], y01)),
                                            pk_mul(zi_p[u], z01));
                const double dot23 = pk_add(pk_add(pk_mul(xi_p[u], x23),
                                                   pk_mul(yi_p[u], y23)),
                                            pk_mul(zi_p[u], z23));
                h[u].d     = pk_fma(dot01, m2, pk_add(ai_p[u], aj01));
                h[4 + u].d = pk_fma(dot23, m2, pk_add(ai_p[u], aj23));
            }
            const float m01 = fminf(fminf(h[0].f[0], h[0].f[1]),
                                    fminf(h[1].f[0], h[1].f[1]));
            const float m23 = fminf(fminf(h[2].f[0], h[2].f[1]),
                                    fminf(h[3].f[0], h[3].f[1]));
            const float m45 = fminf(fminf(h[4].f[0], h[4].f[1]),
                                    fminf(h[5].f[0], h[5].f[1]));
            const float m67 = fminf(fminf(h[6].f[0], h[6].f[1]),
                                    fminf(h[7].f[0], h[7].f[1]));
            float m = fminf(fminf(m01, m23), fminf(m45, m67));
            m = fmaxf(m, 0.0f);
            // Same rounded sqrt as reference (reproduces its near-tie collapse).
            dist[t] = __fsqrt_rn(m);
        }

        // Selection: 16x { f32 wave-min -> ballot-match -> scalar smallest-col }.
        int vcol = 0;
        #pragma unroll 1
        for (int it = 0; it < KK; ++it) {
            float lm = dist[0];
            #pragma unroll
            for (int t = 1; t < 8; ++t) lm = fminf(lm, dist[t]);
            const float m = wave_min_f32(lm);              // uniform
            unsigned long long b[8];
            #pragma unroll
            for (int t = 0; t < 8; ++t) b[t] = __ballot(dist[t] == m);
            int wt = 7; unsigned long long bb = b[7];      // uniform scalar scan
            #pragma unroll
            for (int t = 6; t >= 0; --t) if (b[t] != 0ull) { wt = t; bb = b[t]; }
            const int wl = __ffsll((long long)bb) - 1;
            const int scol = (wt << 6) | wl;               // uniform winner col
            if (lane == it) vcol = scol;
            #pragma unroll
            for (int t = 0; t < 8; ++t)                    // invalidate exactly one
                if (t == wt && lane == wl) dist[t] = __int_as_float(0x7F800000);
        }

        // Outputs (idempotent across reps): row_o, col_o, attr (int32).
        if (lane < KK) {
            const int o = r_global * KK + lane;
            out[o]          = r_global;
            out[NK + o]     = (seg * NPER) + vcol;
            out[2 * NK + o] = 0;
        }

        // Keep reps ordered & prevent cross-rep CSE of the staging/compute.
        __syncthreads();
        asm volatile("" ::: "memory");
    }
}
} // namespace

extern "C" void kernel_launch(void* const* d_in, const int* in_sizes, int n_in,
                              void* d_out, int out_size, void* d_ws, size_t ws_size,
                              hipStream_t stream) {
    const float* unit_pos = (const float*)d_in[0];
    int* out = (int*)d_out;
    hipLaunchKernelGGL(knn_edge_kernel, dim3(NB / 4), dim3(256), 0, stream,
                       unit_pos, out);
}

// Round 9
// 23.339 us; speedup vs baseline: 3.0509x; 3.0509x over previous
//
#include <hip/hip_runtime.h>

namespace {
constexpr int NPER = 512;    // blocks per segment
constexpr int UU   = 4;      // units per block
constexpr int KK   = 16;     // k
constexpr int NB   = 4096;   // total blocks
constexpr int NK   = NB * KK;

// ---- packed dual-f32 (VOP3P). Each half is an exact IEEE _rn f32 op. ----
union pk2 { double d; float f[2]; unsigned u[2]; };

__device__ __forceinline__ double mkpk(float lo, float hi) {
    pk2 t; t.f[0] = lo; t.f[1] = hi; return t.d;
}
__device__ __forceinline__ double pk_mul(double a, double b) {
    double r; asm("v_pk_mul_f32 %0, %1, %2" : "=v"(r) : "v"(a), "v"(b)); return r;
}
__device__ __forceinline__ double pk_add(double a, double b) {
    double r; asm("v_pk_add_f32 %0, %1, %2" : "=v"(r) : "v"(a), "v"(b)); return r;
}
__device__ __forceinline__ double pk_fma(double a, double b, double c) {
    double r; asm("v_pk_fma_f32 %0, %1, %2, %3" : "=v"(r) : "v"(a), "v"(b), "v"(c)); return r;
}

// ---- f32 wave min via DPP: 6 steps x {dpp mov, v_min_f32}; uniform result. ----
__device__ __forceinline__ float wave_min_f32(float v) {
    constexpr int PINF = 0x7F800000;
    int x = __float_as_int(v);
    #define DPP_MIN(CTRL, RM)                                                  \
        x = __float_as_int(fminf(__int_as_float(x), __int_as_float(            \
                __builtin_amdgcn_update_dpp(PINF, x, CTRL, RM, 0xF, false))));
    DPP_MIN(0x111, 0xF)  // row_shr:1
    DPP_MIN(0x112, 0xF)  // row_shr:2
    DPP_MIN(0x114, 0xF)  // row_shr:4
    DPP_MIN(0x118, 0xF)  // row_shr:8
    DPP_MIN(0x142, 0xA)  // row_bcast:15 -> rows 1,3
    DPP_MIN(0x143, 0xC)  // row_bcast:31 -> rows 2,3
    #undef DPP_MIN
    return __int_as_float(__builtin_amdgcn_readlane(x, 63));
}

// Plane-major LDS: 6 planes x 512 doubles (x01,x23,y01,y23,z01,z23) = 24576 B.
// 24.6 KB x 6 WGs = 147 KB < 160 KB -> 6 WGs/CU (vs 4 with the padded AoS
// layout) -> 6 waves/SIMD at VGPR<=85. b64 read banks (2*lane)%32: uniform
// 4 dwords/bank = the wave64 b64 minimum (conflict-floor, same as before).
__global__ __launch_bounds__(256) void knn_edge_kernel(const float* __restrict__ unit_pos,
                                                       int* __restrict__ out) {
    __shared__ double spd[6 * NPER];                 // 24576 B
    float* sfl = reinterpret_cast<float*>(spd);

    const int wg  = blockIdx.x;        // 1024 WGs; 4 rows (waves) each
    const int seg = (wg * 4) >> 9;     // / NPER
    const int tid = threadIdx.x;
    const int wave = tid >> 6;
    const int lane = tid & 63;
    const int r_local  = (wg * 4 + wave) & (NPER - 1);
    const int r_global = seg * NPER + r_local;

    // Stage segment positions into plane-major pk layout.
    // Global float j of candidate c: u=j/3, ax=j%3 ->
    // plane p = ax*2 + (u>>1), slot dword = 2c + (u&1).
    {
        const float4* g4 = reinterpret_cast<const float4*>(
            unit_pos + (size_t)seg * NPER * UU * 3);
        #pragma unroll
        for (int jj = 0; jj < 6; ++jj) {
            const int i4 = tid + 256 * jj;     // float4 index 0..1535
            const float4 v = g4[i4];
            const int c = i4 / 3;
            const int rem = (i4 - 3 * c) * 4;  // 0, 4, or 8
            const float vv[4] = {v.x, v.y, v.z, v.w};
            #pragma unroll
            for (int e = 0; e < 4; ++e) {
                const int j = rem + e, u = j / 3, ax = j - 3 * u;
                sfl[(ax * 2 + (u >> 1)) * 1024 + 2 * c + (u & 1)] = vv[e];
            }
        }
    }
    __syncthreads();

    // Row units duplicated into pk pairs + norms (uniform broadcast reads).
    // Exact reference f32 arithmetic: left-assoc adds, no contraction.
    double xi_p[UU], yi_p[UU], zi_p[UU], ai_p[UU];
    #pragma unroll
    for (int u = 0; u < UU; ++u) {
        const float x = sfl[(0 * 2 + (u >> 1)) * 1024 + 2 * r_local + (u & 1)];
        const float y = sfl[(1 * 2 + (u >> 1)) * 1024 + 2 * r_local + (u & 1)];
        const float z = sfl[(2 * 2 + (u >> 1)) * 1024 + 2 * r_local + (u & 1)];
        const float a = __fadd_rn(__fadd_rn(__fmul_rn(x, x), __fmul_rn(y, y)),
                                  __fmul_rn(z, z));
        xi_p[u] = mkpk(x, x); yi_p[u] = mkpk(y, y);
        zi_p[u] = mkpk(z, z); ai_p[u] = mkpk(a, a);
    }
    const double m2 = mkpk(-2.0f, -2.0f);

    // Each lane owns candidates c = lane + 64*t. Packed halves are the
    // reference's exact f32 ops (left-assoc adds; fma(dot,-2,sum) ==
    // fsub(sum, fmul(2,dot)) since 2*dot is exact).
    float dist[8];
    #pragma unroll
    for (int t = 0; t < 8; ++t) {
        const int c = lane + 64 * t;
        const double x01 = spd[0 * NPER + c], x23 = spd[1 * NPER + c];
        const double y01 = spd[2 * NPER + c], y23 = spd[3 * NPER + c];
        const double z01 = spd[4 * NPER + c], z23 = spd[5 * NPER + c];
        const double aj01 = pk_add(pk_add(pk_mul(x01, x01), pk_mul(y01, y01)),
                                   pk_mul(z01, z01));
        const double aj23 = pk_add(pk_add(pk_mul(x23, x23), pk_mul(y23, y23)),
                                   pk_mul(z23, z23));
        pk2 h[8];
        #pragma unroll
        for (int u = 0; u < UU; ++u) {
            const double dot01 = pk_add(pk_add(pk_mul(xi_p[u], x01),
                                               pk_mul(yi_p[u], y01)),
                                        pk_mul(zi_p[u], z01));
            const double dot23 = pk_add(pk_add(pk_mul(xi_p[u], x23),
                                               pk_mul(yi_p[u], y23)),
                                        pk_mul(zi_p[u], z23));
            h[u].d     = pk_fma(dot01, m2, pk_add(ai_p[u], aj01));
            h[4 + u].d = pk_fma(dot23, m2, pk_add(ai_p[u], aj23));
        }
        // Exact min over 16 d2; deferred clamp commutes with min bit-exactly.
        const float m01 = fminf(fminf(h[0].f[0], h[0].f[1]),
                                fminf(h[1].f[0], h[1].f[1]));
        const float m23 = fminf(fminf(h[2].f[0], h[2].f[1]),
                                fminf(h[3].f[0], h[3].f[1]));
        const float m45 = fminf(fminf(h[4].f[0], h[4].f[1]),
                                fminf(h[5].f[0], h[5].f[1]));
        const float m67 = fminf(fminf(h[6].f[0], h[6].f[1]),
                                fminf(h[7].f[0], h[7].f[1]));
        float m = fminf(fminf(m01, m23), fminf(m45, m67));
        m = fmaxf(m, 0.0f);
        // Same rounded sqrt as reference (reproduces its near-tie collapse;
        // needed so tie-break-by-col fires exactly where the reference ties).
        dist[t] = __fsqrt_rn(m);
    }

    // Selection: 16x { f32 wave-min -> ballot-match -> scalar smallest-col }.
    // Winner = smallest col with dist==m == reference stable (dist, edge-idx)
    // order. Cols are t-major (c = 64t+lane): scan t ascending, lowest lane.
    int vcol = 0;
    #pragma unroll 1
    for (int it = 0; it < KK; ++it) {
        float lm = dist[0];
        #pragma unroll
        for (int t = 1; t < 8; ++t) lm = fminf(lm, dist[t]);
        const float m = wave_min_f32(lm);              // uniform
        unsigned long long b[8];
        #pragma unroll
        for (int t = 0; t < 8; ++t) b[t] = __ballot(dist[t] == m);
        int wt = 7; unsigned long long bb = b[7];      // uniform scalar scan
        #pragma unroll
        for (int t = 6; t >= 0; --t) if (b[t] != 0ull) { wt = t; bb = b[t]; }
        const int wl = __ffsll((long long)bb) - 1;
        const int scol = (wt << 6) | wl;               // uniform winner col
        if (lane == it) vcol = scol;
        #pragma unroll
        for (int t = 0; t < 8; ++t)                    // invalidate exactly one
            if (t == wt && lane == wl) dist[t] = __int_as_float(0x7F800000);
    }

    // Outputs concatenated flat: row_o[65536], col_o[65536], attr[65536] (int32).
    if (lane < KK) {
        const int o = r_global * KK + lane;
        out[o]          = r_global;
        out[NK + o]     = (seg * NPER) + vcol;
        out[2 * NK + o] = 0;
    }
}
} // namespace

extern "C" void kernel_launch(void* const* d_in, const int* in_sizes, int n_in,
                              void* d_out, int out_size, void* d_ws, size_t ws_size,
                              hipStream_t stream) {
    const float* unit_pos = (const float*)d_in[0];
    int* out = (int*)d_out;
    hipLaunchKernelGGL(knn_edge_kernel, dim3(NB / 4), dim3(256), 0, stream,
                       unit_pos, out);
}

// Round 10
// 20.967 us; speedup vs baseline: 3.3960x; 1.1131x over previous
//
#include <hip/hip_runtime.h>

namespace {
constexpr int NPER = 512;    // blocks per segment
constexpr int UU   = 4;      // units per block
constexpr int KK   = 16;     // k
constexpr int NB   = 4096;   // total blocks
constexpr int NK   = NB * KK;

// ---- packed dual-f32 (VOP3P). Each half is an exact IEEE _rn f32 op. ----
union pk2 { double d; float f[2]; unsigned u[2]; };

__device__ __forceinline__ double mkpk(float lo, float hi) {
    pk2 t; t.f[0] = lo; t.f[1] = hi; return t.d;
}
__device__ __forceinline__ double pk_mul(double a, double b) {
    double r; asm("v_pk_mul_f32 %0, %1, %2" : "=v"(r) : "v"(a), "v"(b)); return r;
}
__device__ __forceinline__ double pk_add(double a, double b) {
    double r; asm("v_pk_add_f32 %0, %1, %2" : "=v"(r) : "v"(a), "v"(b)); return r;
}
__device__ __forceinline__ double pk_fma(double a, double b, double c) {
    double r; asm("v_pk_fma_f32 %0, %1, %2, %3" : "=v"(r) : "v"(a), "v"(b), "v"(c)); return r;
}

// ---- f32 wave min via DPP: 6 steps x {dpp mov, v_min_f32}; uniform result. ----
__device__ __forceinline__ float wave_min_f32(float v) {
    constexpr int PINF = 0x7F800000;
    int x = __float_as_int(v);
    #define DPP_MIN(CTRL, RM)                                                  \
        x = __float_as_int(fminf(__int_as_float(x), __int_as_float(            \
                __builtin_amdgcn_update_dpp(PINF, x, CTRL, RM, 0xF, false))));
    DPP_MIN(0x111, 0xF)  // row_shr:1
    DPP_MIN(0x112, 0xF)  // row_shr:2
    DPP_MIN(0x114, 0xF)  // row_shr:4
    DPP_MIN(0x118, 0xF)  // row_shr:8
    DPP_MIN(0x142, 0xA)  // row_bcast:15 -> rows 1,3
    DPP_MIN(0x143, 0xC)  // row_bcast:31 -> rows 2,3
    #undef DPP_MIN
    return __int_as_float(__builtin_amdgcn_readlane(x, 63));
}

// LDS layout: per-block 48B line [x01 x23 | y01 y23 | z01 z23] (b128-readable,
// granule 3c mod 8 bijective -> bank-floor) + two dense 8B-stride norm planes
// ajA (aj01) and ajB (aj23). Total 32768 B. Occupancy is grid-capped at
// 4 waves/SIMD (4096 waves / 1024 SIMDs) -- LDS/VGPR can't change it (R9).
__global__ __launch_bounds__(256) void knn_edge_kernel(const float* __restrict__ unit_pos,
                                                       int* __restrict__ out) {
    __shared__ __align__(16) double S[NPER * 6 + NPER + NPER];   // 32768 B

    const int wg  = blockIdx.x;        // 1024 WGs; 4 rows (waves) each
    const int seg = (wg * 4) >> 9;     // / NPER
    const int tid = threadIdx.x;
    const int wave = tid >> 6;
    const int lane = tid & 63;
    const int r_local  = (wg * 4 + wave) & (NPER - 1);
    const int r_global = seg * NPER + r_local;

    // ---- Staging: 2 blocks/thread; contiguous float4 loads, register
    // permute into pk pairs, 3x ds_write_b128 + 2 norm writes per block. ----
    {
        const float4* g4 = reinterpret_cast<const float4*>(
            unit_pos + (size_t)seg * NPER * UU * 3);
        #pragma unroll
        for (int b = 0; b < 2; ++b) {
            const int c = tid + 256 * b;
            const float4 v0 = g4[3 * c + 0];   // x0 y0 z0 x1
            const float4 v1 = g4[3 * c + 1];   // y1 z1 x2 y2
            const float4 v2 = g4[3 * c + 2];   // z2 x3 y3 z3
            const double x01 = mkpk(v0.x, v0.w);
            const double x23 = mkpk(v1.z, v2.y);
            const double y01 = mkpk(v0.y, v1.x);
            const double y23 = mkpk(v1.w, v2.z);
            const double z01 = mkpk(v0.z, v1.y);
            const double z23 = mkpk(v2.x, v2.w);
            // Candidate norms, exact reference f32 sequence per half
            // (left-assoc adds, no contraction).
            const double aj01 = pk_add(pk_add(pk_mul(x01, x01), pk_mul(y01, y01)),
                                       pk_mul(z01, z01));
            const double aj23 = pk_add(pk_add(pk_mul(x23, x23), pk_mul(y23, y23)),
                                       pk_mul(z23, z23));
            double2* blk = reinterpret_cast<double2*>(&S[6 * c]);
            blk[0] = make_double2(x01, x23);
            blk[1] = make_double2(y01, y23);
            blk[2] = make_double2(z01, z23);
            S[6 * NPER + c] = aj01;
            S[7 * NPER + c] = aj23;
        }
    }
    __syncthreads();

    // Row units as duplicated pk pairs + scalar norms (uniform broadcasts;
    // exact reference f32 arithmetic).
    double xi_p[UU], yi_p[UU], zi_p[UU], ai_p[UU];
    {
        const float* rp = reinterpret_cast<const float*>(&S[6 * r_local]);
        #pragma unroll
        for (int u = 0; u < UU; ++u) {
            const float x = rp[u], y = rp[4 + u], z = rp[8 + u];
            const float a = __fadd_rn(__fadd_rn(__fmul_rn(x, x), __fmul_rn(y, y)),
                                      __fmul_rn(z, z));
            xi_p[u] = mkpk(x, x); yi_p[u] = mkpk(y, y);
            zi_p[u] = mkpk(z, z); ai_p[u] = mkpk(a, a);
        }
    }
    const double m2 = mkpk(-2.0f, -2.0f);

    // Each lane owns candidates c = lane + 64*t. Packed halves are the
    // reference's exact f32 ops (fma(dot,-2,sum) == fsub(sum, fmul(2,dot))
    // since 2*dot is exact). Norms pre-staged; min chain is exact (order-free,
    // written flat so clang fuses v_min3_f32).
    float dist[8];
    #pragma unroll
    for (int t = 0; t < 8; ++t) {
        const int c = lane + 64 * t;
        const double2 d0 = *reinterpret_cast<const double2*>(&S[6 * c]);
        const double2 d1 = *reinterpret_cast<const double2*>(&S[6 * c + 2]);
        const double2 d2 = *reinterpret_cast<const double2*>(&S[6 * c + 4]);
        const double aj01 = S[6 * NPER + c];
        const double aj23 = S[7 * NPER + c];
        pk2 h[8];
        #pragma unroll
        for (int u = 0; u < UU; ++u) {
            const double dot01 = pk_add(pk_add(pk_mul(xi_p[u], d0.x),
                                               pk_mul(yi_p[u], d1.x)),
                                        pk_mul(zi_p[u], d2.x));
            const double dot23 = pk_add(pk_add(pk_mul(xi_p[u], d0.y),
                                               pk_mul(yi_p[u], d1.y)),
                                        pk_mul(zi_p[u], d2.y));
            h[u].d     = pk_fma(dot01, m2, pk_add(ai_p[u], aj01));
            h[4 + u].d = pk_fma(dot23, m2, pk_add(ai_p[u], aj23));
        }
        float m = h[0].f[0];
        m = fminf(m, h[0].f[1]); m = fminf(m, h[1].f[0]); m = fminf(m, h[1].f[1]);
        m = fminf(m, h[2].f[0]); m = fminf(m, h[2].f[1]); m = fminf(m, h[3].f[0]);
        m = fminf(m, h[3].f[1]); m = fminf(m, h[4].f[0]); m = fminf(m, h[4].f[1]);
        m = fminf(m, h[5].f[0]); m = fminf(m, h[5].f[1]); m = fminf(m, h[6].f[0]);
        m = fminf(m, h[6].f[1]); m = fminf(m, h[7].f[0]); m = fminf(m, h[7].f[1]);
        m = fmaxf(m, 0.0f);
        // Same rounded sqrt as reference (reproduces its near-tie collapse;
        // needed so tie-break-by-col fires exactly where the reference ties).
        dist[t] = __fsqrt_rn(m);
    }

    // Selection: 16x { f32 wave-min -> ballot-match -> scalar smallest-col }.
    // Winner = smallest col with dist==m == reference stable (dist, edge-idx)
    // order. Cols are t-major (c = 64t+lane): scan t ascending, lowest lane.
    int vcol = 0;
    #pragma unroll 1
    for (int it = 0; it < KK; ++it) {
        float lm = dist[0];
        lm = fminf(lm, dist[1]); lm = fminf(lm, dist[2]); lm = fminf(lm, dist[3]);
        lm = fminf(lm, dist[4]); lm = fminf(lm, dist[5]); lm = fminf(lm, dist[6]);
        lm = fminf(lm, dist[7]);
        const float m = wave_min_f32(lm);              // uniform
        unsigned long long b[8];
        #pragma unroll
        for (int t = 0; t < 8; ++t) b[t] = __ballot(dist[t] == m);
        int wt = 7; unsigned long long bb = b[7];      // uniform scalar scan
        #pragma unroll
        for (int t = 6; t >= 0; --t) if (b[t] != 0ull) { wt = t; bb = b[t]; }
        const int wl = __ffsll((long long)bb) - 1;
        const int scol = (wt << 6) | wl;               // uniform winner col
        if (lane == it) vcol = scol;
        #pragma unroll
        for (int t = 0; t < 8; ++t)                    // invalidate exactly one
            if (t == wt && lane == wl) dist[t] = __int_as_float(0x7F800000);
    }

    // Outputs concatenated flat: row_o[65536], col_o[65536], attr[65536] (int32).
    if (lane < KK) {
        const int o = r_global * KK + lane;
        out[o]          = r_global;
        out[NK + o]     = (seg * NPER) + vcol;
        out[2 * NK + o] = 0;
    }
}
} // namespace

extern "C" void kernel_launch(void* const* d_in, const int* in_sizes, int n_in,
                              void* d_out, int out_size, void* d_ws, size_t ws_size,
                              hipStream_t stream) {
    const float* unit_pos = (const float*)d_in[0];
    int* out = (int*)d_out;
    hipLaunchKernelGGL(knn_edge_kernel, dim3(NB / 4), dim3(256), 0, stream,
                       unit_pos, out);
}

// Round 11
// 20.617 us; speedup vs baseline: 3.4537x; 1.0170x over previous
//
#include <hip/hip_runtime.h>

namespace {
constexpr int NPER = 512;    // blocks per segment
constexpr int UU   = 4;      // units per block
constexpr int KK   = 16;     // k
constexpr int NB   = 4096;   // total blocks
constexpr int NK   = NB * KK;

// ---- packed dual-f32 (VOP3P). Each half is an exact IEEE _rn f32 op. ----
union pk2 { double d; float f[2]; unsigned u[2]; };

__device__ __forceinline__ double mkpk(float lo, float hi) {
    pk2 t; t.f[0] = lo; t.f[1] = hi; return t.d;
}
__device__ __forceinline__ double pk_mul(double a, double b) {
    double r; asm("v_pk_mul_f32 %0, %1, %2" : "=v"(r) : "v"(a), "v"(b)); return r;
}
__device__ __forceinline__ double pk_add(double a, double b) {
    double r; asm("v_pk_add_f32 %0, %1, %2" : "=v"(r) : "v"(a), "v"(b)); return r;
}
__device__ __forceinline__ double pk_fma(double a, double b, double c) {
    double r; asm("v_pk_fma_f32 %0, %1, %2, %3" : "=v"(r) : "v"(a), "v"(b), "v"(c)); return r;
}

// ---- f32 wave min via DPP: 6 steps x {dpp mov, v_min_f32}; uniform result.
// (Kept as builtins: hand-fused v_min_f32_dpp would skip the compiler's DPP
// hazard handling -- not worth the risk for ~6 slots.) ----
__device__ __forceinline__ float wave_min_f32(float v) {
    constexpr int PINF = 0x7F800000;
    int x = __float_as_int(v);
    #define DPP_MIN(CTRL, RM)                                                  \
        x = __float_as_int(fminf(__int_as_float(x), __int_as_float(            \
                __builtin_amdgcn_update_dpp(PINF, x, CTRL, RM, 0xF, false))));
    DPP_MIN(0x111, 0xF)  // row_shr:1
    DPP_MIN(0x112, 0xF)  // row_shr:2
    DPP_MIN(0x114, 0xF)  // row_shr:4
    DPP_MIN(0x118, 0xF)  // row_shr:8
    DPP_MIN(0x142, 0xA)  // row_bcast:15 -> rows 1,3
    DPP_MIN(0x143, 0xC)  // row_bcast:31 -> rows 2,3
    #undef DPP_MIN
    return __int_as_float(__builtin_amdgcn_readlane(x, 63));
}

// WG=1024 (16 rows), grid=256: staging runs on waves 0-7 only (amortized 4x
// vs WG=256) and the dispatch stream shrinks 4x. Residency unchanged:
// 16 waves/WG on 4 SIMDs = 4 waves/SIMD (grid-capped; R9 showed LDS/VGPR
// can't raise it). LDS: per-block 48B line [x01 x23|y01 y23|z01 z23]
// (3x b128, granule 3c mod 8 bijective -> bank-floor) + dense (aj01,aj23)
// double2 plane (1x b128). Total 32768 B.
__global__ __launch_bounds__(1024) void knn_edge_kernel(const float* __restrict__ unit_pos,
                                                        int* __restrict__ out) {
    __shared__ __align__(16) double S[NPER * 6 + NPER * 2];      // 32768 B

    const int wg  = blockIdx.x;        // 256 WGs; 16 rows (waves) each
    const int seg = wg >> 5;           // 32 WGs per segment
    const int tid = threadIdx.x;
    const int wave = tid >> 6;
    const int lane = tid & 63;
    const int r_local  = (wg * 16 + wave) & (NPER - 1);
    const int r_global = seg * NPER + r_local;

    // ---- Staging: one block per thread for tid<512; contiguous float4
    // loads, register permute into pk pairs, 4x ds_write_b128 per block. ----
    if (tid < NPER) {
        const float4* g4 = reinterpret_cast<const float4*>(
            unit_pos + (size_t)seg * NPER * UU * 3);
        const int c = tid;
        const float4 v0 = g4[3 * c + 0];   // x0 y0 z0 x1
        const float4 v1 = g4[3 * c + 1];   // y1 z1 x2 y2
        const float4 v2 = g4[3 * c + 2];   // z2 x3 y3 z3
        const double x01 = mkpk(v0.x, v0.w);
        const double x23 = mkpk(v1.z, v2.y);
        const double y01 = mkpk(v0.y, v1.x);
        const double y23 = mkpk(v1.w, v2.z);
        const double z01 = mkpk(v0.z, v1.y);
        const double z23 = mkpk(v2.x, v2.w);
        // Candidate norms, exact reference f32 sequence per half
        // (left-assoc adds, no contraction).
        const double aj01 = pk_add(pk_add(pk_mul(x01, x01), pk_mul(y01, y01)),
                                   pk_mul(z01, z01));
        const double aj23 = pk_add(pk_add(pk_mul(x23, x23), pk_mul(y23, y23)),
                                   pk_mul(z23, z23));
        double2* blk = reinterpret_cast<double2*>(&S[6 * c]);
        blk[0] = make_double2(x01, x23);
        blk[1] = make_double2(y01, y23);
        blk[2] = make_double2(z01, z23);
        *reinterpret_cast<double2*>(&S[6 * NPER + 2 * c]) = make_double2(aj01, aj23);
    }
    __syncthreads();

    // Row units as duplicated pk pairs + scalar norms (uniform broadcasts;
    // exact reference f32 arithmetic).
    double xi_p[UU], yi_p[UU], zi_p[UU], ai_p[UU];
    {
        const float* rp = reinterpret_cast<const float*>(&S[6 * r_local]);
        #pragma unroll
        for (int u = 0; u < UU; ++u) {
            const float x = rp[u], y = rp[4 + u], z = rp[8 + u];
            const float a = __fadd_rn(__fadd_rn(__fmul_rn(x, x), __fmul_rn(y, y)),
                                      __fmul_rn(z, z));
            xi_p[u] = mkpk(x, x); yi_p[u] = mkpk(y, y);
            zi_p[u] = mkpk(z, z); ai_p[u] = mkpk(a, a);
        }
    }
    const double m2 = mkpk(-2.0f, -2.0f);

    // Each lane owns candidates c = lane + 64*t. Packed halves are the
    // reference's exact f32 ops (fma(dot,-2,sum) == fsub(sum, fmul(2,dot))
    // since 2*dot is exact). Norms pre-staged; flat min chain is exact
    // (order-free) and fuses to v_min3_f32.
    float dist[8];
    #pragma unroll
    for (int t = 0; t < 8; ++t) {
        const int c = lane + 64 * t;
        const double2 d0 = *reinterpret_cast<const double2*>(&S[6 * c]);
        const double2 d1 = *reinterpret_cast<const double2*>(&S[6 * c + 2]);
        const double2 d2 = *reinterpret_cast<const double2*>(&S[6 * c + 4]);
        const double2 ajp = *reinterpret_cast<const double2*>(&S[6 * NPER + 2 * c]);
        pk2 h[8];
        #pragma unroll
        for (int u = 0; u < UU; ++u) {
            const double dot01 = pk_add(pk_add(pk_mul(xi_p[u], d0.x),
                                               pk_mul(yi_p[u], d1.x)),
                                        pk_mul(zi_p[u], d2.x));
            const double dot23 = pk_add(pk_add(pk_mul(xi_p[u], d0.y),
                                               pk_mul(yi_p[u], d1.y)),
                                        pk_mul(zi_p[u], d2.y));
            h[u].d     = pk_fma(dot01, m2, pk_add(ai_p[u], ajp.x));
            h[4 + u].d = pk_fma(dot23, m2, pk_add(ai_p[u], ajp.y));
        }
        float m = h[0].f[0];
        m = fminf(m, h[0].f[1]); m = fminf(m, h[1].f[0]); m = fminf(m, h[1].f[1]);
        m = fminf(m, h[2].f[0]); m = fminf(m, h[2].f[1]); m = fminf(m, h[3].f[0]);
        m = fminf(m, h[3].f[1]); m = fminf(m, h[4].f[0]); m = fminf(m, h[4].f[1]);
        m = fminf(m, h[5].f[0]); m = fminf(m, h[5].f[1]); m = fminf(m, h[6].f[0]);
        m = fminf(m, h[6].f[1]); m = fminf(m, h[7].f[0]); m = fminf(m, h[7].f[1]);
        m = fmaxf(m, 0.0f);
        // Same rounded sqrt as reference (reproduces its near-tie collapse;
        // needed so tie-break-by-col fires exactly where the reference ties).
        dist[t] = __fsqrt_rn(m);
    }

    // Selection: 16x { f32 wave-min -> ballot-match -> scalar smallest-col }.
    // Winner = smallest col with dist==m == reference stable (dist, edge-idx)
    // order. Cols are t-major (c = 64t+lane): scan t ascending, lowest lane.
    int vcol = 0;
    #pragma unroll 1
    for (int it = 0; it < KK; ++it) {
        float lm = dist[0];
        lm = fminf(lm, dist[1]); lm = fminf(lm, dist[2]); lm = fminf(lm, dist[3]);
        lm = fminf(lm, dist[4]); lm = fminf(lm, dist[5]); lm = fminf(lm, dist[6]);
        lm = fminf(lm, dist[7]);
        const float m = wave_min_f32(lm);              // uniform
        unsigned long long b[8];
        #pragma unroll
        for (int t = 0; t < 8; ++t) b[t] = __ballot(dist[t] == m);
        int wt = 7; unsigned long long bb = b[7];      // uniform scalar scan
        #pragma unroll
        for (int t = 6; t >= 0; --t) if (b[t] != 0ull) { wt = t; bb = b[t]; }
        const int wl = __ffsll((long long)bb) - 1;
        const int scol = (wt << 6) | wl;               // uniform winner col
        if (lane == it) vcol = scol;
        #pragma unroll
        for (int t = 0; t < 8; ++t)                    // invalidate exactly one
            if (t == wt && lane == wl) dist[t] = __int_as_float(0x7F800000);
    }

    // Outputs concatenated flat: row_o[65536], col_o[65536], attr[65536] (int32).
    if (lane < KK) {
        const int o = r_global * KK + lane;
        out[o]          = r_global;
        out[NK + o]     = (seg * NPER) + vcol;
        out[2 * NK + o] = 0;
    }
}
} // namespace

extern "C" void kernel_launch(void* const* d_in, const int* in_sizes, int n_in,
                              void* d_out, int out_size, void* d_ws, size_t ws_size,
                              hipStream_t stream) {
    const float* unit_pos = (const float*)d_in[0];
    int* out = (int*)d_out;
    hipLaunchKernelGGL(knn_edge_kernel, dim3(NB / 16), dim3(1024), 0, stream,
                       unit_pos, out);
}